// Round 4
// baseline (324.797 us; speedup 1.0000x reference)
//
#include <hip/hip_runtime.h>

#define GRIDX 128
#define CCH 64

// coords row: (b, x, y, z) as int4
__global__ void build_table_kernel(const int4* __restrict__ coords,
                                   int* __restrict__ table, int n) {
    int i = blockIdx.x * blockDim.x + threadIdx.x;
    if (i >= n) return;
    int4 cc = coords[i];
    // key = ((b*G + x)*G + y)*G + z ; G=128 -> shifts
    int key = (cc.x << 21) | (cc.y << 14) | (cc.z << 7) | cc.w;
    table[key] = i + 1;  // 0 means "absent"
}

__global__ void upsample_kernel(const int4* __restrict__ coords,
                                const float4* __restrict__ feats,   // N x 16 float4
                                const float4* __restrict__ dflt,    // 16 float4
                                const int* __restrict__ table,
                                float4* __restrict__ out,           // (N*8) x 16 float4
                                int n) {
    int t = blockIdx.x * blockDim.x + threadIdx.x;
    int r = t >> 4;           // output voxel row in [0, n*8)
    int cg = t & 15;          // float4 channel group
    if (r >= n * 8) return;
    int i = r >> 3;
    int o = r & 7;            // (ox,oy,oz) = (o>>2&1, o>>1&1, o&1), meshgrid ij order
    int4 cc = coords[i];
    int b = cc.x, x = cc.y, y = cc.z, z = cc.w;
    int ox = (o >> 2) & 1, oy = (o >> 1) & 1, oz = o & 1;
    // S=2: src = coord + off/2 - 0.25 => base = coord-1+off, weight(base) = off?0.75:0.25
    int bx = x - 1 + ox, by = y - 1 + oy, bz = z - 1 + oz;
    float wx0 = ox ? 0.75f : 0.25f;
    float wy0 = oy ? 0.75f : 0.25f;
    float wz0 = oz ? 0.75f : 0.25f;
    float4 dv = dflt[cg];
    float4 acc = {0.f, 0.f, 0.f, 0.f};
    int bkey = b << 21;
    #pragma unroll
    for (int k = 0; k < 8; ++k) {
        int dx = (k >> 2) & 1, dy = (k >> 1) & 1, dz = k & 1;
        int cx = bx + dx, cy = by + dy, cz = bz + dz;
        float w = (dx ? 1.f - wx0 : wx0) *
                  (dy ? 1.f - wy0 : wy0) *
                  (dz ? 1.f - wz0 : wz0);
        float4 g = dv;
        if ((unsigned)cx < GRIDX && (unsigned)cy < GRIDX && (unsigned)cz < GRIDX) {
            int key = bkey | (cx << 14) | (cy << 7) | cz;
            int v = table[key];
            if (v > 0) g = feats[(size_t)(v - 1) * 16 + cg];
        }
        acc.x += w * g.x;
        acc.y += w * g.y;
        acc.z += w * g.z;
        acc.w += w * g.w;
    }
    out[(size_t)r * 16 + cg] = acc;
}

extern "C" void kernel_launch(void* const* d_in, const int* in_sizes, int n_in,
                              void* d_out, int out_size, void* d_ws, size_t ws_size,
                              hipStream_t stream) {
    const int4*   coords = (const int4*)d_in[0];
    const float4* feats  = (const float4*)d_in[1];
    const float4* dflt   = (const float4*)d_in[2];
    float4*       out    = (float4*)d_out;
    int n = in_sizes[0] / 4;                      // N points
    int* table = (int*)d_ws;
    const size_t table_bytes = (size_t)2 * GRIDX * GRIDX * GRIDX * sizeof(int); // 16 MB (B=2)

    hipMemsetAsync(d_ws, 0, table_bytes, stream);
    build_table_kernel<<<(n + 255) / 256, 256, 0, stream>>>(coords, table, n);

    long long total = (long long)n * 8 * 16;      // 16 lanes per output row
    int blocks = (int)((total + 255) / 256);
    upsample_kernel<<<blocks, 256, 0, stream>>>(coords, feats, dflt, table, out, n);
}

// Round 5
// 290.373 us; speedup vs baseline: 1.1186x; 1.1186x over previous
//
#include <hip/hip_runtime.h>

#define G 128
// bitmap: 2*128^3 bits = 524288 bytes; table: 2*128^3 * 4B = 16 MB (never cleared)
#define BITMAP_BYTES (2u * G * G * G / 8u)

__global__ void build_kernel(const int4* __restrict__ coords,
                             unsigned* __restrict__ bitmap,
                             int* __restrict__ table, int n) {
    int i = blockIdx.x * blockDim.x + threadIdx.x;
    if (i >= n) return;
    int4 c = coords[i];
    int key = (c.x << 21) | (c.y << 14) | (c.z << 7) | c.w;
    table[key] = i;
    atomicOr(&bitmap[key >> 5], 1u << (key & 31));
}

__global__ void upsample_kernel(const int4* __restrict__ coords,
                                const float4* __restrict__ feats,   // N x 16 float4
                                const float4* __restrict__ dflt,    // 16 float4
                                const unsigned* __restrict__ bitmap,
                                const int* __restrict__ table,
                                float4* __restrict__ out,           // (N*8) x 16 float4
                                int n) {
    int t = blockIdx.x * blockDim.x + threadIdx.x;
    int i = t >> 4;           // point index
    int cg = t & 15;          // float4 channel group
    if (i >= n) return;
    int4 c = coords[i];
    int b = c.x, x = c.y, y = c.z, z = c.w;
    float4 d = dflt[cg];
    float4 f = feats[(size_t)i * 16 + cg];
    // parent corner has per-axis weight 0.75 for every fine voxel -> w = 0.421875
    float4 base;
    base.x = d.x + 0.421875f * (f.x - d.x);
    base.y = d.y + 0.421875f * (f.y - d.y);
    base.z = d.z + 0.421875f * (f.z - d.z);
    base.w = d.w + 0.421875f * (f.w - d.w);
    float4 acc[8];
    #pragma unroll
    for (int o = 0; o < 8; ++o) acc[o] = base;

    int bbase = b << 21;
    #pragma unroll
    for (int ei = 0; ei < 27; ++ei) {
        if (ei == 13) continue;  // parent handled in init
        const int ex = ei / 9 - 1;
        const int ey = (ei / 3) % 3 - 1;
        const int ez = ei % 3 - 1;
        int nx = x + ex, ny = y + ey, nz = z + ez;
        bool valid = ((unsigned)nx < G) & ((unsigned)ny < G) & ((unsigned)nz < G);
        int key = bbase | ((nx & (G - 1)) << 14) | ((ny & (G - 1)) << 7) | (nz & (G - 1));
        unsigned wrd = bitmap[key >> 5];   // unconditional, clamped key is in-range
        if (valid && ((wrd >> (key & 31)) & 1u)) {
            int idx = table[key];
            float4 g = feats[(size_t)idx * 16 + cg];
            const float w = ((ex == 0) ? 0.75f : 0.25f) *
                            ((ey == 0) ? 0.75f : 0.25f) *
                            ((ez == 0) ? 0.75f : 0.25f);
            float4 delta;
            delta.x = w * (g.x - d.x);
            delta.y = w * (g.y - d.y);
            delta.z = w * (g.z - d.z);
            delta.w = w * (g.w - d.w);
            const int x0 = (ex == 1) ? 1 : 0, x1 = (ex == -1) ? 0 : 1;
            const int y0 = (ey == 1) ? 1 : 0, y1 = (ey == -1) ? 0 : 1;
            const int z0 = (ez == 1) ? 1 : 0, z1 = (ez == -1) ? 0 : 1;
            #pragma unroll
            for (int ox = x0; ox <= x1; ++ox)
                #pragma unroll
                for (int oy = y0; oy <= y1; ++oy)
                    #pragma unroll
                    for (int oz = z0; oz <= z1; ++oz) {
                        int o = ox * 4 + oy * 2 + oz;
                        acc[o].x += delta.x;
                        acc[o].y += delta.y;
                        acc[o].z += delta.z;
                        acc[o].w += delta.w;
                    }
        }
    }
    size_t rbase = ((size_t)i * 8) * 16 + cg;
    #pragma unroll
    for (int o = 0; o < 8; ++o) out[rbase + o * 16] = acc[o];
}

extern "C" void kernel_launch(void* const* d_in, const int* in_sizes, int n_in,
                              void* d_out, int out_size, void* d_ws, size_t ws_size,
                              hipStream_t stream) {
    const int4*   coords = (const int4*)d_in[0];
    const float4* feats  = (const float4*)d_in[1];
    const float4* dflt   = (const float4*)d_in[2];
    float4*       out    = (float4*)d_out;
    int n = in_sizes[0] / 4;

    unsigned* bitmap = (unsigned*)d_ws;
    int* table = (int*)((char*)d_ws + BITMAP_BYTES);   // 16 MB, intentionally NOT cleared

    hipMemsetAsync(bitmap, 0, BITMAP_BYTES, stream);   // 512 KB only
    build_kernel<<<(n + 255) / 256, 256, 0, stream>>>(coords, bitmap, table, n);

    long long total = (long long)n * 16;               // 16 lanes per point
    int blocks = (int)((total + 255) / 256);
    upsample_kernel<<<blocks, 256, 0, stream>>>(coords, feats, dflt, bitmap, table, out, n);
}

// Round 6
// 257.425 us; speedup vs baseline: 1.2617x; 1.1280x over previous
//
#include <hip/hip_runtime.h>

#define G 128
// bitmap: 2*128^3 bits = 512 KB (cleared each launch); table: 16 MB (never cleared)
#define BITMAP_BYTES (2u * G * G * G / 8u)

__global__ void build_kernel(const int4* __restrict__ coords,
                             unsigned* __restrict__ bitmap,
                             int* __restrict__ table, int n) {
    int i = blockIdx.x * blockDim.x + threadIdx.x;
    if (i >= n) return;
    int4 c = coords[i];
    int key = (c.x << 21) | (c.y << 14) | (c.z << 7) | c.w;
    table[key] = i;
    atomicOr(&bitmap[key >> 5], 1u << (key & 31));
}

// Apply one shared hit (packed p) to the accumulators.
#define APPLY_HIT(p)                                                        \
    {                                                                       \
        int idx = (int)((p) >> 8) - 1;                                      \
        unsigned om = (p) & 255u;                                           \
        int pc = __popc(om);                                                \
        float w = (pc == 4) ? 0.140625f : ((pc == 2) ? 0.046875f : 0.015625f); \
        float4 g4 = feats[(size_t)idx * 16 + cg];                           \
        float ddx = w * (g4.x - d4.x), ddy = w * (g4.y - d4.y);             \
        float ddz = w * (g4.z - d4.z), ddw = w * (g4.w - d4.w);             \
        _Pragma("unroll")                                                   \
        for (int o = 0; o < 8; ++o) {                                       \
            float s = (float)((om >> o) & 1u);                              \
            acc[o].x += s * ddx; acc[o].y += s * ddy;                       \
            acc[o].z += s * ddz; acc[o].w += s * ddw;                       \
        }                                                                   \
    }

__global__ __launch_bounds__(256) void upsample_kernel(
        const int4* __restrict__ coords,
        const float4* __restrict__ feats,   // N x 16 float4
        const float4* __restrict__ dflt,    // 16 float4
        const unsigned* __restrict__ bitmap,
        const int* __restrict__ table,
        float4* __restrict__ out,           // (N*8) x 16 float4
        int n) {
    int t = blockIdx.x * blockDim.x + threadIdx.x;
    int i = t >> 4;           // point index (16 lanes per point)
    int cg = t & 15;          // float4 channel group
    if (i >= n) return;
    int lane = threadIdx.x & 63;
    int g = lane >> 4;        // group within wave (4 points per wave)
    int l = lane & 15;        // lane within group

    int4 c = coords[i];
    int x = c.y, y = c.z, z = c.w;
    int bbase = c.x << 21;

    // ---- probe phase: lanes 0..12 each probe directions l and l+14 (center=13 skipped)
    unsigned packed0 = 0u, packed1 = 0u;
    if (l < 13) {
        #pragma unroll
        for (int r = 0; r < 2; ++r) {
            int di = l + (r ? 14 : 0);
            int ex = di / 9 - 1;
            int ey = (di / 3) % 3 - 1;
            int ez = di % 3 - 1;
            int nx = x + ex, ny = y + ey, nz = z + ez;
            bool valid = ((unsigned)nx < G) & ((unsigned)ny < G) & ((unsigned)nz < G);
            int key = valid ? (bbase | (nx << 14) | (ny << 7) | nz) : bbase;
            unsigned wrd = bitmap[key >> 5];
            unsigned p = 0u;
            if (valid && ((wrd >> (key & 31)) & 1u)) {
                int idx = table[key];
                // 2-bit per-axis octant masks: -1 -> {0}, 0 -> {0,1}, +1 -> {1}
                unsigned xm = (ex == 0) ? 3u : ((ex < 0) ? 1u : 2u);
                unsigned ym = (ey == 0) ? 3u : ((ey < 0) ? 1u : 2u);
                unsigned zm = (ez == 0) ? 3u : ((ez < 0) ? 1u : 2u);
                unsigned myz = ((ym & 1u) ? zm : 0u) | ((ym & 2u) ? (zm << 2) : 0u);
                unsigned om  = ((xm & 1u) ? myz : 0u) | ((xm & 2u) ? (myz << 4) : 0u);
                p = ((unsigned)(idx + 1) << 8) | om;
            }
            if (r) packed1 = p; else packed0 = p;
        }
    }
    unsigned long long bal0 = __ballot(packed0 != 0u);
    unsigned long long bal1 = __ballot(packed1 != 0u);

    // ---- base: default + parent contribution (weight 0.75^3 for all 8 octants)
    float4 d4 = dflt[cg];
    float4 f4 = feats[(size_t)i * 16 + cg];
    float4 base;
    base.x = d4.x + 0.421875f * (f4.x - d4.x);
    base.y = d4.y + 0.421875f * (f4.y - d4.y);
    base.z = d4.z + 0.421875f * (f4.z - d4.z);
    base.w = d4.w + 0.421875f * (f4.w - d4.w);
    float4 acc[8];
    #pragma unroll
    for (int o = 0; o < 8; ++o) acc[o] = base;

    // ---- apply phase: iterate this group's hits (expected ~0.6 per point)
    unsigned m0 = (unsigned)((bal0 >> (g * 16)) & 0x1FFFull);
    unsigned m1 = (unsigned)((bal1 >> (g * 16)) & 0x1FFFull);
    while (m0) {
        int j = __ffs(m0) - 1; m0 &= m0 - 1;
        unsigned p = (unsigned)__shfl((int)packed0, (g << 4) + j, 64);
        APPLY_HIT(p);
    }
    while (m1) {
        int j = __ffs(m1) - 1; m1 &= m1 - 1;
        unsigned p = (unsigned)__shfl((int)packed1, (g << 4) + j, 64);
        APPLY_HIT(p);
    }

    size_t rbase = (size_t)i * 128 + cg;   // in float4 units
    #pragma unroll
    for (int o = 0; o < 8; ++o) out[rbase + o * 16] = acc[o];
}

extern "C" void kernel_launch(void* const* d_in, const int* in_sizes, int n_in,
                              void* d_out, int out_size, void* d_ws, size_t ws_size,
                              hipStream_t stream) {
    const int4*   coords = (const int4*)d_in[0];
    const float4* feats  = (const float4*)d_in[1];
    const float4* dflt   = (const float4*)d_in[2];
    float4*       out    = (float4*)d_out;
    int n = in_sizes[0] / 4;

    unsigned* bitmap = (unsigned*)d_ws;
    int* table = (int*)((char*)d_ws + BITMAP_BYTES);   // read only where bitmap bit set

    hipMemsetAsync(bitmap, 0, BITMAP_BYTES, stream);   // 512 KB only
    build_kernel<<<(n + 255) / 256, 256, 0, stream>>>(coords, bitmap, table, n);

    long long total = (long long)n * 16;               // 16 lanes per point
    int blocks = (int)((total + 255) / 256);
    upsample_kernel<<<blocks, 256, 0, stream>>>(coords, feats, dflt, bitmap, table, out, n);
}